// Round 4
// baseline (430.503 us; speedup 1.0000x reference)
//
#include <hip/hip_runtime.h>
#include <hip/hip_bf16.h>
#include <stdint.h>

// SparseSelfAttention on MI355X, round 4.
// Algebra: att = softmax(Wq G Wk^T), G = X X^T per batch (SYMMETRIC -> upper tiles only);
//          out = (W_out att_bd Wv) X + (W_out att_bd b_v + b_out)
// All GEMMs NT-form, pure-bf16 inputs (hi/lo split precomputed), global_load_lds staging.
// Tile aspect ratios chosen per-GEMM to minimize HBM strip re-fetch.

#define NSPAT 4096
#define SPARS 0.1f

typedef __attribute__((ext_vector_type(8))) short bf16x8;
typedef __attribute__((ext_vector_type(4))) float f32x4;

static __device__ __forceinline__ unsigned short f2bf(float f) {
  unsigned u = __float_as_uint(f);
  unsigned r = u + 0x7fffu + ((u >> 16) & 1u);   // RN-even (finite inputs)
  return (unsigned short)(r >> 16);
}
static __device__ __forceinline__ float bf2f(unsigned short s) {
  return __uint_as_float(((unsigned)s) << 16);
}

static __device__ __forceinline__ void gld16(const unsigned short* g, unsigned short* l) {
  __builtin_amdgcn_global_load_lds(
      (const __attribute__((address_space(1))) void*)g,
      (__attribute__((address_space(3))) void*)l, 16, 0, 0);
}

// NT GEMM: C[m,n] = sum_k A[m,k]*B[n,k] (+bias_m[z*sbias+m]) (+bias_n[n]).
// Inputs bf16. NPROD==3: split A=(Ah+Al), B=(Bh+Bl), drop Al*Bl term.
// COUT: 0=f32, 1=bf16, 2=bf16 hi/lo pair (Cv,Cv2).
// SYM: A==B square (TM==TN), blockIdx.x in [0,10) decodes upper-triangle 4x4 tile.
// Tile TM x TN, BK=32, 256 threads (4 waves 2x2), global_load_lds staging.
template<int TM, int TN, int NPROD, int COUT, int SYM>
__global__ __launch_bounds__(256)
void gemm_bt(const unsigned short* Ahg, const unsigned short* Alg,
             const unsigned short* Bhg, const unsigned short* Blg,
             void* Cv, void* Cv2,
             int K, int lda, int ldb, int ldc,
             int amod, int bmod, int cmod,
             long long sA, long long sA2, long long sB, long long sB2,
             long long sC, long long sC2,
             const float* bias_m, long long sbias, const float* bias_n)
{
  constexpr int MT = TM / 32;
  constexpr int NT = TN / 32;
  __shared__ __align__(16) unsigned short Ah[TM * 32];
  __shared__ __align__(16) unsigned short Bh[TN * 32];
  __shared__ __align__(16) unsigned short Al[NPROD == 3 ? TM * 32 : 8];
  __shared__ __align__(16) unsigned short Bl[NPROD == 3 ? TN * 32 : 8];

  const int tid = threadIdx.x;
  const int z = blockIdx.z;
  int m0, n0;
  if (SYM) {
    int t = blockIdx.x;
    int ti = (t < 4) ? 0 : (t < 7) ? 1 : (t < 9) ? 2 : 3;
    int tj = (t < 4) ? t : (t < 7) ? (t - 3) : (t < 9) ? (t - 5) : 3;
    m0 = ti * TM; n0 = tj * TN;
  } else {
    m0 = blockIdx.y * TM; n0 = blockIdx.x * TN;
  }

  const unsigned short* Ab  = Ahg + (size_t)(z % amod) * sA + (size_t)(z / amod) * sA2;
  const unsigned short* Bb  = Bhg + (size_t)(z % bmod) * sB + (size_t)(z / bmod) * sB2;
  const unsigned short* Abl = Alg + (size_t)(z % amod) * sA + (size_t)(z / amod) * sA2;
  const unsigned short* Bbl = Blg + (size_t)(z % bmod) * sB + (size_t)(z / bmod) * sB2;
  char* Cb = (char*)Cv + ((size_t)(z % cmod) * sC + (size_t)(z / cmod) * sC2) * (COUT == 0 ? 4 : 2);
  char* Cb2 = (char*)Cv2 + ((size_t)(z % cmod) * sC + (size_t)(z / cmod) * sC2) * 2;

  const int lane = tid & 63, wave = tid >> 6;
  const int wm = wave >> 1, wn = wave & 1;
  const int kq = lane >> 4, l16 = lane & 15;
  const int rsub = lane >> 2, ko = (lane & 3) * 8;   // staging: 4 rows x 32k per 16 lanes

  f32x4 acc[MT][NT];
  for (int i = 0; i < MT; ++i)
    for (int j = 0; j < NT; ++j)
      for (int r = 0; r < 4; ++r) acc[i][j][r] = 0.f;

  for (int k0 = 0; k0 < K; k0 += 32) {
    for (int i = 0; i < TM / 64; ++i) {
      int q = wave * (TM / 64) + i;
      size_t go = (size_t)(m0 + q * 16 + rsub) * lda + k0 + ko;
      gld16(Ab + go, &Ah[q * 512]);
      if (NPROD == 3) gld16(Abl + go, &Al[q * 512]);
    }
    for (int i = 0; i < TN / 64; ++i) {
      int q = wave * (TN / 64) + i;
      size_t go = (size_t)(n0 + q * 16 + rsub) * ldb + k0 + ko;
      gld16(Bb + go, &Bh[q * 512]);
      if (NPROD == 3) gld16(Bbl + go, &Bl[q * 512]);
    }
    __syncthreads();

    bf16x8 af[MT], bf[NT], afl[MT], bfl[NT];
    for (int t = 0; t < MT; ++t) {
      af[t] = *(const bf16x8*)&Ah[(wm * (TM / 2) + t * 16 + l16) * 32 + kq * 8];
      if (NPROD == 3) afl[t] = *(const bf16x8*)&Al[(wm * (TM / 2) + t * 16 + l16) * 32 + kq * 8];
    }
    for (int t = 0; t < NT; ++t) {
      bf[t] = *(const bf16x8*)&Bh[(wn * (TN / 2) + t * 16 + l16) * 32 + kq * 8];
      if (NPROD == 3) bfl[t] = *(const bf16x8*)&Bl[(wn * (TN / 2) + t * 16 + l16) * 32 + kq * 8];
    }
    for (int mt = 0; mt < MT; ++mt)
      for (int nt = 0; nt < NT; ++nt) {
        acc[mt][nt] = __builtin_amdgcn_mfma_f32_16x16x32_bf16(af[mt], bf[nt], acc[mt][nt], 0, 0, 0);
        if (NPROD == 3) {
          acc[mt][nt] = __builtin_amdgcn_mfma_f32_16x16x32_bf16(af[mt], bfl[nt], acc[mt][nt], 0, 0, 0);
          acc[mt][nt] = __builtin_amdgcn_mfma_f32_16x16x32_bf16(afl[mt], bf[nt], acc[mt][nt], 0, 0, 0);
        }
      }
    __syncthreads();
  }

  // C/D layout: col=lane&15, row=(lane>>4)*4+r
  for (int mt = 0; mt < MT; ++mt)
    for (int nt = 0; nt < NT; ++nt)
      for (int r = 0; r < 4; ++r) {
        int m = m0 + wm * (TM / 2) + mt * 16 + kq * 4 + r;
        int n = n0 + wn * (TN / 2) + nt * 16 + l16;
        float v = acc[mt][nt][r];
        if (bias_m) v += bias_m[(size_t)z * sbias + m];
        if (bias_n) v += bias_n[n];
        if (COUT == 0) ((float*)Cb)[(size_t)m * ldc + n] = v;
        else if (COUT == 1) ((unsigned short*)Cb)[(size_t)m * ldc + n] = f2bf(v);
        else {
          unsigned short h = f2bf(v);
          ((unsigned short*)Cb)[(size_t)m * ldc + n] = h;
          ((unsigned short*)Cb2)[(size_t)m * ldc + n] = f2bf(v - bf2f(h));
        }
      }
}

// x (b,512,4096) fp32 -> Xhi,Xlo (b,512,4096) bf16 + Xt (b,4096,512) bf16
__global__ __launch_bounds__(256)
void prep_x(const float* __restrict__ x, unsigned short* __restrict__ Xhi,
            unsigned short* __restrict__ Xlo, unsigned short* __restrict__ Xt)
{
  __shared__ float tile[32][33];
  int b = blockIdx.z;
  int n0 = blockIdx.x * 32, c0 = blockIdx.y * 32;
  const float* X = x + (size_t)b * 512 * NSPAT;
  for (int i = threadIdx.y; i < 32; i += 8) {
    float v = X[(size_t)(c0 + i) * NSPAT + n0 + threadIdx.x];
    tile[i][threadIdx.x] = v;
    size_t o = (size_t)b * 2097152 + (size_t)(c0 + i) * NSPAT + n0 + threadIdx.x;
    unsigned short h = f2bf(v);
    Xhi[o] = h;
    Xlo[o] = f2bf(v - bf2f(h));
  }
  __syncthreads();
  unsigned short* O = Xt + (size_t)b * NSPAT * 512;
  for (int i = threadIdx.y; i < 32; i += 8)
    O[(size_t)(n0 + i) * 512 + c0 + threadIdx.x] = f2bf(tile[threadIdx.x][i]);
}

// fp32 -> bf16 hi/lo split, float4-vectorized; n4 = elements/4
__global__ __launch_bounds__(256)
void split_w(const float* __restrict__ w, unsigned short* __restrict__ hi,
             unsigned short* __restrict__ lo, int n4)
{
  int i = blockIdx.x * 256 + threadIdx.x;
  if (i >= n4) return;
  float4 f = ((const float4*)w)[i];
  unsigned short h0 = f2bf(f.x), h1 = f2bf(f.y), h2 = f2bf(f.z), h3 = f2bf(f.w);
  ((ushort4*)hi)[i] = make_ushort4(h0, h1, h2, h3);
  ((ushort4*)lo)[i] = make_ushort4(f2bf(f.x - bf2f(h0)), f2bf(f.y - bf2f(h1)),
                                   f2bf(f.z - bf2f(h2)), f2bf(f.w - bf2f(h3)));
}

// Wv (1024x512 fp32) -> WvT (512x1024 bf16)
__global__ __launch_bounds__(256)
void transpose_wv(const float* __restrict__ wv, unsigned short* __restrict__ WvT)
{
  __shared__ float t[32][33];
  int k0 = blockIdx.x * 32, e0 = blockIdx.y * 32;
  for (int i = threadIdx.y; i < 32; i += 8)
    t[i][threadIdx.x] = wv[(size_t)(e0 + i) * 512 + k0 + threadIdx.x];
  __syncthreads();
  for (int i = threadIdx.y; i < 32; i += 8)
    WvT[(size_t)(k0 + i) * 1024 + e0 + threadIdx.x] = f2bf(t[threadIdx.x][i]);
}

// Sum 4 K-chunks of Gpart (upper-triangle tiles only) -> Ghi/Glo full (mirrored).
// grid (10 tiles, 8 b), 256 thr. Gpart[chunk][b][512][512], chunk stride 2097152, b 262144.
__global__ __launch_bounds__(256)
void reduce_g_sym(const float* __restrict__ Gp, unsigned short* __restrict__ Ghi,
                  unsigned short* __restrict__ Glo)
{
  int t = blockIdx.x, b = blockIdx.y;
  int ti = (t < 4) ? 0 : (t < 7) ? 1 : (t < 9) ? 2 : 3;
  int tj = (t < 4) ? t : (t < 7) ? (t - 3) : (t < 9) ? (t - 5) : 3;
  __shared__ float lds[64][132];
  const float* base = Gp + (size_t)b * 262144;
  unsigned short* Hb = Ghi + (size_t)b * 262144;
  unsigned short* Lb = Glo + (size_t)b * 262144;
  const int tid = threadIdx.x;
  const int row = tid >> 2, q = tid & 3;     // 64 rows x 4 col-groups (32 each)
  const int mrow = tid >> 1, q2 = tid & 1;   // 128 rows x 2 col-groups (32 each)

  for (int half = 0; half < 2; ++half) {
    int r0 = ti * 128 + half * 64;
    for (int j = 0; j < 4; ++j) {            // 8 cols per j
      int c = tj * 128 + q * 32 + j * 8;
      size_t idx = (size_t)(r0 + row) * 512 + c;
      float4 s0 = *(const float4*)(base + idx);
      float4 s1 = *(const float4*)(base + idx + 4);
      for (int ch = 1; ch < 4; ++ch) {
        float4 a0 = *(const float4*)(base + (size_t)ch * 2097152 + idx);
        float4 a1 = *(const float4*)(base + (size_t)ch * 2097152 + idx + 4);
        s0.x += a0.x; s0.y += a0.y; s0.z += a0.z; s0.w += a0.w;
        s1.x += a1.x; s1.y += a1.y; s1.z += a1.z; s1.w += a1.w;
      }
      float v[8] = {s0.x, s0.y, s0.z, s0.w, s1.x, s1.y, s1.z, s1.w};
      bf16x8 hi8, lo8;
      for (int k = 0; k < 8; ++k) {
        unsigned short h = f2bf(v[k]);
        hi8[k] = (short)h; lo8[k] = (short)f2bf(v[k] - bf2f(h));
      }
      *(bf16x8*)&Hb[idx] = hi8;
      *(bf16x8*)&Lb[idx] = lo8;
      if (ti != tj)
        for (int k = 0; k < 8; ++k) lds[row][q * 32 + j * 8 + k] = v[k];
    }
    if (ti != tj) {
      __syncthreads();
      for (int j = 0; j < 4; ++j) {
        int rr = q2 * 32 + j * 8;            // r-offset within half
        bf16x8 hi8, lo8;
        for (int k = 0; k < 8; ++k) {
          float v = lds[rr + k][mrow];
          unsigned short h = f2bf(v);
          hi8[k] = (short)h; lo8[k] = (short)f2bf(v - bf2f(h));
        }
        size_t idx = (size_t)(tj * 128 + mrow) * 512 + r0 + rr;
        *(bf16x8*)&Hb[idx] = hi8;
        *(bf16x8*)&Lb[idx] = lo8;
      }
      __syncthreads();
    }
  }
}

// per (b,h): att = softmax(logits rows) * (mask<0.1); store transposed, split bf16
__global__ __launch_bounds__(128)
void softmax_mask(const float* __restrict__ logits, const float* __restrict__ mask_u,
                  unsigned short* __restrict__ aTh, unsigned short* __restrict__ aTl)
{
  int z = blockIdx.x;          // b*8+h
  int d = threadIdx.x;         // row
  const float* row = logits + (size_t)z * 16384 + (size_t)d * 128;
  const float* mrow = mask_u + (size_t)z * 16384 + (size_t)d * 128;
  float mx = -3.4e38f;
  for (int e = 0; e < 128; ++e) mx = fmaxf(mx, row[e]);
  float s = 0.f;
  for (int e = 0; e < 128; ++e) s += __expf(row[e] - mx);
  float inv = 1.f / s;
  for (int e = 0; e < 128; ++e) {
    float a = __expf(row[e] - mx) * inv;
    a = (mrow[e] < SPARS) ? a : 0.f;
    unsigned short h = f2bf(a);
    aTh[(size_t)z * 16384 + (size_t)e * 128 + d] = h;
    aTl[(size_t)z * 16384 + (size_t)e * 128 + d] = f2bf(a - bf2f(h));
  }
}

// vb[b][c] = b_out[c] + sum_e Mh[b][c][e] * b_v[e]; one wave per (b,c)
__global__ __launch_bounds__(256)
void vbias_k(const unsigned short* __restrict__ Mh, const float* __restrict__ bv,
             const float* __restrict__ b_out, float* __restrict__ vb)
{
  int w = threadIdx.x >> 6, l = threadIdx.x & 63;
  int c = blockIdx.x * 4 + w;
  int b = blockIdx.y;
  const unsigned short* row = Mh + (size_t)b * 524288 + (size_t)c * 1024;
  float s = 0.f;
  for (int e = l; e < 1024; e += 64) s += bf2f(row[e]) * bv[e];
  for (int off = 32; off; off >>= 1) s += __shfl_down(s, off, 64);
  if (l == 0) vb[b * 512 + c] = b_out[c] + s;
}

extern "C" void kernel_launch(void* const* d_in, const int* in_sizes, int n_in,
                              void* d_out, int out_size, void* d_ws, size_t ws_size,
                              hipStream_t stream)
{
  const float* x      = (const float*)d_in[0];
  const float* w_qkv  = (const float*)d_in[1];
  const float* b_qkv  = (const float*)d_in[2];
  const float* w_out  = (const float*)d_in[3];
  const float* b_out  = (const float*)d_in[4];
  const float* mask_u = (const float*)d_in[5];
  float* out = (float*)d_out;
  (void)in_sizes; (void)n_in; (void)out_size; (void)ws_size;

  char* ws = (char*)d_ws;
  unsigned short* Xt   = (unsigned short*)ws;                    // 33,554,432
  unsigned short* Xhi  = (unsigned short*)(ws + 33554432);       // 33,554,432 (dead after G)
  unsigned short* Xlo  = (unsigned short*)(ws + 67108864);       // 33,554,432 (dead after G)
  unsigned short* Tph  = (unsigned short*)(ws + 33554432);       //  8,388,608 (overlay Xhi)
  unsigned short* Tpl  = (unsigned short*)(ws + 41943040);       //  8,388,608
  float*          Lg   = (float*)(ws + 50331648);                //  4,194,304
  unsigned short* aTh  = (unsigned short*)(ws + 54525952);       //  2,097,152
  unsigned short* aTl  = (unsigned short*)(ws + 56623104);       //  2,097,152
  unsigned short* Mh   = (unsigned short*)(ws + 67108864);       //  8,388,608 (overlay Xlo)
  unsigned short* P    = (unsigned short*)(ws + 75497472);       //  4,194,304
  float*          vb   = (float*)(ws + 79691776);                //     16,384
  float*          Gpart= (float*)(ws + 100663296);               // 33,554,432 (dead after reduce)
  unsigned short* Ghi  = (unsigned short*)(ws + 134217728);      //  4,194,304
  unsigned short* Glo  = (unsigned short*)(ws + 138412032);      //  4,194,304
  unsigned short* Whi  = (unsigned short*)(ws + 142606336);      //  3,145,728
  unsigned short* Wlo  = (unsigned short*)(ws + 145752064);      //  3,145,728
  unsigned short* Ohi  = (unsigned short*)(ws + 148897792);      //  1,048,576
  unsigned short* Olo  = (unsigned short*)(ws + 149946368);      //  1,048,576
  unsigned short* WvT  = Whi + 1048576;                          // reuse Whi's V rows

  const int BIG = 1 << 30;

  // 1. split+transpose x
  prep_x<<<dim3(128, 16, 8), dim3(32, 8), 0, stream>>>(x, Xhi, Xlo, Xt);
  // 2. split weights; WvT AFTER split_w (overwrites Whi's V rows)
  split_w<<<dim3(1536), 256, 0, stream>>>(w_qkv, Whi, Wlo, 393216);
  split_w<<<dim3(512), 256, 0, stream>>>(w_out, Ohi, Olo, 131072);
  transpose_wv<<<dim3(16, 32), dim3(32, 8), 0, stream>>>(w_qkv + 1048576, WvT);

  // 3. Gpart[chunk][b] = Xb Xb^T, K-split 4, UPPER-TRIANGLE tiles only (SYM)
  gemm_bt<128, 128, 3, 0, 1><<<dim3(10, 1, 32), 256, 0, stream>>>(
      Xhi, Xlo, Xhi, Xlo, Gpart, nullptr,
      1024, 4096, 4096, 512, 8, 8, 8,
      2097152LL, 1024LL, 2097152LL, 1024LL, 262144LL, 2097152LL, nullptr, 0LL, nullptr);

  // 4. reduce chunks + mirror lower triangle -> Ghi/Glo
  reduce_g_sym<<<dim3(10, 8), 256, 0, stream>>>(Gpart, Ghi, Glo);

  // 5. Tp_b = Wq * G_b (G symmetric -> NT), split out. 256x64 tiles (G-strip reuse)
  gemm_bt<256, 64, 3, 2, 0><<<dim3(8, 4, 8), 256, 0, stream>>>(
      Whi, Wlo, Ghi, Glo, Tph, Tpl,
      512, 512, 512, 512, 1, 8, 8,
      0LL, 0LL, 262144LL, 0LL, 524288LL, 0LL, nullptr, 0LL, nullptr);

  // 6. L_{b,h} = Tp_{b,h} * Wk_h^T  (z=b*8+h)
  gemm_bt<64, 64, 3, 0, 0><<<dim3(2, 2, 64), 256, 0, stream>>>(
      Tph, Tpl, Whi + 524288, Wlo + 524288, Lg, nullptr,
      512, 512, 512, 128, BIG, 8, BIG,
      65536LL, 0LL, 65536LL, 0LL, 16384LL, 0LL, nullptr, 0LL, nullptr);

  // 7. softmax + mask -> attT hi/lo
  softmax_mask<<<dim3(64), 128, 0, stream>>>(Lg, mask_u, aTh, aTl);

  // 8. M_{b,h}[c,e'] = sum_d w_out[c,h*128+d] attT[e',d]  (z=b*8+h)
  gemm_bt<64, 64, 3, 1, 0><<<dim3(2, 8, 64), 256, 0, stream>>>(
      Ohi, Olo, aTh, aTl, Mh, nullptr,
      128, 1024, 128, 1024, 8, BIG, 8,
      128LL, 0LL, 16384LL, 0LL, 128LL, 524288LL, nullptr, 0LL, nullptr);

  // 9. vb[b][c] = b_out[c] + Mh_b[c,:] . b_v
  vbias_k<<<dim3(128, 8), 256, 0, stream>>>(Mh, b_qkv + 2048, b_out, vb);

  // 10. P_b[c,k] = sum_e Mh_b[c,e] WvT[k,e]  (plain bf16). 64x128 tiles (Mh reuse)
  gemm_bt<64, 128, 1, 1, 0><<<dim3(4, 8, 8), 256, 0, stream>>>(
      Mh, Mh, WvT, WvT, P, nullptr,
      1024, 1024, 1024, 512, BIG, 1, BIG,
      524288LL, 0LL, 0LL, 0LL, 262144LL, 0LL, nullptr, 0LL, nullptr);

  // 11. out_b[c,n] = sum_k P_b[c,k] Xt_b[n,k] + vb[b][c]. 256x64 tiles (Xt-strip reuse)
  gemm_bt<256, 64, 1, 0, 0><<<dim3(64, 2, 8), 256, 0, stream>>>(
      P, P, Xt, Xt, out, nullptr,
      512, 512, 512, 4096, BIG, BIG, BIG,
      262144LL, 0LL, 2097152LL, 0LL, 2097152LL, 0LL, vb, 512LL, nullptr);
}

// Round 5
// 378.850 us; speedup vs baseline: 1.1363x; 1.1363x over previous
//
#include <hip/hip_runtime.h>
#include <hip/hip_bf16.h>
#include <stdint.h>

// SparseSelfAttention on MI355X, round 5.
// Algebra: att = softmax(Wq G Wk^T), G = X X^T per batch (SYMMETRIC -> upper tiles only);
//          out = (W_out att_bd Wv) X + (W_out att_bd b_v + b_out)
// All GEMMs NT-form, bf16 inputs (hi/lo split precomputed), global_load_lds staging.
// Round-5: tile shapes back to >=2 blocks/CU configs (r4's skinny tiles died of
// 1-wave/SIMD latency exposure); prep_x fully vectorized.

#define NSPAT 4096
#define SPARS 0.1f

typedef __attribute__((ext_vector_type(8))) short bf16x8;
typedef __attribute__((ext_vector_type(4))) float f32x4;

static __device__ __forceinline__ unsigned short f2bf(float f) {
  unsigned u = __float_as_uint(f);
  unsigned r = u + 0x7fffu + ((u >> 16) & 1u);   // RN-even (finite inputs)
  return (unsigned short)(r >> 16);
}
static __device__ __forceinline__ float bf2f(unsigned short s) {
  return __uint_as_float(((unsigned)s) << 16);
}

static __device__ __forceinline__ void gld16(const unsigned short* g, unsigned short* l) {
  __builtin_amdgcn_global_load_lds(
      (const __attribute__((address_space(1))) void*)g,
      (__attribute__((address_space(3))) void*)l, 16, 0, 0);
}

// NT GEMM: C[m,n] = sum_k A[m,k]*B[n,k] (+bias_m[z*sbias+m]) (+bias_n[n]).
// Inputs bf16. NPROD==3: split A=(Ah+Al), B=(Bh+Bl), drop Al*Bl term.
// COUT: 0=f32, 1=bf16, 2=bf16 hi/lo pair (Cv,Cv2).
// SYM: A==B square (TM==TN), blockIdx.x in [0,10) decodes upper-triangle 4x4 tile.
template<int TM, int TN, int NPROD, int COUT, int SYM>
__global__ __launch_bounds__(256)
void gemm_bt(const unsigned short* Ahg, const unsigned short* Alg,
             const unsigned short* Bhg, const unsigned short* Blg,
             void* Cv, void* Cv2,
             int K, int lda, int ldb, int ldc,
             int amod, int bmod, int cmod,
             long long sA, long long sA2, long long sB, long long sB2,
             long long sC, long long sC2,
             const float* bias_m, long long sbias, const float* bias_n)
{
  constexpr int MT = TM / 32;
  constexpr int NT = TN / 32;
  __shared__ __align__(16) unsigned short Ah[TM * 32];
  __shared__ __align__(16) unsigned short Bh[TN * 32];
  __shared__ __align__(16) unsigned short Al[NPROD == 3 ? TM * 32 : 8];
  __shared__ __align__(16) unsigned short Bl[NPROD == 3 ? TN * 32 : 8];

  const int tid = threadIdx.x;
  const int z = blockIdx.z;
  int m0, n0;
  if (SYM) {
    int t = blockIdx.x;
    int ti = (t < 4) ? 0 : (t < 7) ? 1 : (t < 9) ? 2 : 3;
    int tj = (t < 4) ? t : (t < 7) ? (t - 3) : (t < 9) ? (t - 5) : 3;
    m0 = ti * TM; n0 = tj * TN;
  } else {
    m0 = blockIdx.y * TM; n0 = blockIdx.x * TN;
  }

  const unsigned short* Ab  = Ahg + (size_t)(z % amod) * sA + (size_t)(z / amod) * sA2;
  const unsigned short* Bb  = Bhg + (size_t)(z % bmod) * sB + (size_t)(z / bmod) * sB2;
  const unsigned short* Abl = Alg + (size_t)(z % amod) * sA + (size_t)(z / amod) * sA2;
  const unsigned short* Bbl = Blg + (size_t)(z % bmod) * sB + (size_t)(z / bmod) * sB2;
  char* Cb = (char*)Cv + ((size_t)(z % cmod) * sC + (size_t)(z / cmod) * sC2) * (COUT == 0 ? 4 : 2);
  char* Cb2 = (char*)Cv2 + ((size_t)(z % cmod) * sC + (size_t)(z / cmod) * sC2) * 2;

  const int lane = tid & 63, wave = tid >> 6;
  const int wm = wave >> 1, wn = wave & 1;
  const int kq = lane >> 4, l16 = lane & 15;
  const int rsub = lane >> 2, ko = (lane & 3) * 8;   // staging: 4 rows x 32k per 16 lanes

  f32x4 acc[MT][NT];
  for (int i = 0; i < MT; ++i)
    for (int j = 0; j < NT; ++j)
      for (int r = 0; r < 4; ++r) acc[i][j][r] = 0.f;

  for (int k0 = 0; k0 < K; k0 += 32) {
    for (int i = 0; i < TM / 64; ++i) {
      int q = wave * (TM / 64) + i;
      size_t go = (size_t)(m0 + q * 16 + rsub) * lda + k0 + ko;
      gld16(Ab + go, &Ah[q * 512]);
      if (NPROD == 3) gld16(Abl + go, &Al[q * 512]);
    }
    for (int i = 0; i < TN / 64; ++i) {
      int q = wave * (TN / 64) + i;
      size_t go = (size_t)(n0 + q * 16 + rsub) * ldb + k0 + ko;
      gld16(Bb + go, &Bh[q * 512]);
      if (NPROD == 3) gld16(Bbl + go, &Bl[q * 512]);
    }
    __syncthreads();

    bf16x8 af[MT], bf[NT], afl[MT], bfl[NT];
    for (int t = 0; t < MT; ++t) {
      af[t] = *(const bf16x8*)&Ah[(wm * (TM / 2) + t * 16 + l16) * 32 + kq * 8];
      if (NPROD == 3) afl[t] = *(const bf16x8*)&Al[(wm * (TM / 2) + t * 16 + l16) * 32 + kq * 8];
    }
    for (int t = 0; t < NT; ++t) {
      bf[t] = *(const bf16x8*)&Bh[(wn * (TN / 2) + t * 16 + l16) * 32 + kq * 8];
      if (NPROD == 3) bfl[t] = *(const bf16x8*)&Bl[(wn * (TN / 2) + t * 16 + l16) * 32 + kq * 8];
    }
    for (int mt = 0; mt < MT; ++mt)
      for (int nt = 0; nt < NT; ++nt) {
        acc[mt][nt] = __builtin_amdgcn_mfma_f32_16x16x32_bf16(af[mt], bf[nt], acc[mt][nt], 0, 0, 0);
        if (NPROD == 3) {
          acc[mt][nt] = __builtin_amdgcn_mfma_f32_16x16x32_bf16(af[mt], bfl[nt], acc[mt][nt], 0, 0, 0);
          acc[mt][nt] = __builtin_amdgcn_mfma_f32_16x16x32_bf16(afl[mt], bf[nt], acc[mt][nt], 0, 0, 0);
        }
      }
    __syncthreads();
  }

  // C/D layout: col=lane&15, row=(lane>>4)*4+r
  for (int mt = 0; mt < MT; ++mt)
    for (int nt = 0; nt < NT; ++nt)
      for (int r = 0; r < 4; ++r) {
        int m = m0 + wm * (TM / 2) + mt * 16 + kq * 4 + r;
        int n = n0 + wn * (TN / 2) + nt * 16 + l16;
        float v = acc[mt][nt][r];
        if (bias_m) v += bias_m[(size_t)z * sbias + m];
        if (bias_n) v += bias_n[n];
        if (COUT == 0) ((float*)Cb)[(size_t)m * ldc + n] = v;
        else if (COUT == 1) ((unsigned short*)Cb)[(size_t)m * ldc + n] = f2bf(v);
        else {
          unsigned short h = f2bf(v);
          ((unsigned short*)Cb)[(size_t)m * ldc + n] = h;
          ((unsigned short*)Cb2)[(size_t)m * ldc + n] = f2bf(v - bf2f(h));
        }
      }
}

// x (b,512,4096) fp32 -> Xhi,Xlo (b,512,4096) bf16 + Xt (b,4096,512) bf16.
// Block: 32 c-rows x 128 n-cols. float4 loads, ushort4 stores, b128 Xt stores.
__global__ __launch_bounds__(256)
void prep_x(const float* __restrict__ x, unsigned short* __restrict__ Xhi,
            unsigned short* __restrict__ Xlo, unsigned short* __restrict__ Xt)
{
  __shared__ float tile[32][136];
  const int b = blockIdx.z;
  const int n0 = blockIdx.x * 128, c0 = blockIdx.y * 32;
  const float* X = x + (size_t)b * 512 * NSPAT;
  const int r8 = threadIdx.x >> 5;          // 0..7
  const int qd = threadIdx.x & 31;          // float4 index within 128 cols
  for (int i = 0; i < 4; ++i) {
    int c = i * 8 + r8;
    size_t src = (size_t)(c0 + c) * NSPAT + n0 + qd * 4;
    float4 f = *(const float4*)&X[src];
    unsigned short h0 = f2bf(f.x), h1 = f2bf(f.y), h2 = f2bf(f.z), h3 = f2bf(f.w);
    size_t o = (size_t)b * 2097152 + src;
    *(ushort4*)&Xhi[o] = make_ushort4(h0, h1, h2, h3);
    *(ushort4*)&Xlo[o] = make_ushort4(f2bf(f.x - bf2f(h0)), f2bf(f.y - bf2f(h1)),
                                      f2bf(f.z - bf2f(h2)), f2bf(f.w - bf2f(h3)));
    *(float4*)&tile[c][qd * 4] = f;
  }
  __syncthreads();
  const int n = threadIdx.x >> 1, half = threadIdx.x & 1;   // n in 0..127
  bf16x8 v0, v1;
  for (int j = 0; j < 8; ++j) {
    v0[j] = (short)f2bf(tile[half * 16 + j][n]);
    v1[j] = (short)f2bf(tile[half * 16 + 8 + j][n]);
  }
  unsigned short* O = Xt + (size_t)b * 2097152 + (size_t)(n0 + n) * 512 + c0 + half * 16;
  *(bf16x8*)O = v0;
  *(bf16x8*)(O + 8) = v1;
}

// fp32 -> bf16 hi/lo split, float4-vectorized; n4 = elements/4
__global__ __launch_bounds__(256)
void split_w(const float* __restrict__ w, unsigned short* __restrict__ hi,
             unsigned short* __restrict__ lo, int n4)
{
  int i = blockIdx.x * 256 + threadIdx.x;
  if (i >= n4) return;
  float4 f = ((const float4*)w)[i];
  unsigned short h0 = f2bf(f.x), h1 = f2bf(f.y), h2 = f2bf(f.z), h3 = f2bf(f.w);
  ((ushort4*)hi)[i] = make_ushort4(h0, h1, h2, h3);
  ((ushort4*)lo)[i] = make_ushort4(f2bf(f.x - bf2f(h0)), f2bf(f.y - bf2f(h1)),
                                   f2bf(f.z - bf2f(h2)), f2bf(f.w - bf2f(h3)));
}

// Wv (1024x512 fp32) -> WvT (512x1024 bf16)
__global__ __launch_bounds__(256)
void transpose_wv(const float* __restrict__ wv, unsigned short* __restrict__ WvT)
{
  __shared__ float t[32][33];
  int k0 = blockIdx.x * 32, e0 = blockIdx.y * 32;
  for (int i = threadIdx.y; i < 32; i += 8)
    t[i][threadIdx.x] = wv[(size_t)(e0 + i) * 512 + k0 + threadIdx.x];
  __syncthreads();
  for (int i = threadIdx.y; i < 32; i += 8)
    WvT[(size_t)(k0 + i) * 1024 + e0 + threadIdx.x] = f2bf(t[threadIdx.x][i]);
}

// Sum 4 K-chunks of Gpart (upper-triangle tiles only) -> Ghi/Glo full (mirrored).
__global__ __launch_bounds__(256)
void reduce_g_sym(const float* __restrict__ Gp, unsigned short* __restrict__ Ghi,
                  unsigned short* __restrict__ Glo)
{
  int t = blockIdx.x, b = blockIdx.y;
  int ti = (t < 4) ? 0 : (t < 7) ? 1 : (t < 9) ? 2 : 3;
  int tj = (t < 4) ? t : (t < 7) ? (t - 3) : (t < 9) ? (t - 5) : 3;
  __shared__ float lds[64][132];
  const float* base = Gp + (size_t)b * 262144;
  unsigned short* Hb = Ghi + (size_t)b * 262144;
  unsigned short* Lb = Glo + (size_t)b * 262144;
  const int tid = threadIdx.x;
  const int row = tid >> 2, q = tid & 3;
  const int mrow = tid >> 1, q2 = tid & 1;

  for (int half = 0; half < 2; ++half) {
    int r0 = ti * 128 + half * 64;
    for (int j = 0; j < 4; ++j) {
      int c = tj * 128 + q * 32 + j * 8;
      size_t idx = (size_t)(r0 + row) * 512 + c;
      float4 s0 = *(const float4*)(base + idx);
      float4 s1 = *(const float4*)(base + idx + 4);
      for (int ch = 1; ch < 4; ++ch) {
        float4 a0 = *(const float4*)(base + (size_t)ch * 2097152 + idx);
        float4 a1 = *(const float4*)(base + (size_t)ch * 2097152 + idx + 4);
        s0.x += a0.x; s0.y += a0.y; s0.z += a0.z; s0.w += a0.w;
        s1.x += a1.x; s1.y += a1.y; s1.z += a1.z; s1.w += a1.w;
      }
      float v[8] = {s0.x, s0.y, s0.z, s0.w, s1.x, s1.y, s1.z, s1.w};
      bf16x8 hi8, lo8;
      for (int k = 0; k < 8; ++k) {
        unsigned short h = f2bf(v[k]);
        hi8[k] = (short)h; lo8[k] = (short)f2bf(v[k] - bf2f(h));
      }
      *(bf16x8*)&Hb[idx] = hi8;
      *(bf16x8*)&Lb[idx] = lo8;
      if (ti != tj)
        for (int k = 0; k < 8; ++k) lds[row][q * 32 + j * 8 + k] = v[k];
    }
    if (ti != tj) {
      __syncthreads();
      for (int j = 0; j < 4; ++j) {
        int rr = q2 * 32 + j * 8;
        bf16x8 hi8, lo8;
        for (int k = 0; k < 8; ++k) {
          float v = lds[rr + k][mrow];
          unsigned short h = f2bf(v);
          hi8[k] = (short)h; lo8[k] = (short)f2bf(v - bf2f(h));
        }
        size_t idx = (size_t)(tj * 128 + mrow) * 512 + r0 + rr;
        *(bf16x8*)&Hb[idx] = hi8;
        *(bf16x8*)&Lb[idx] = lo8;
      }
      __syncthreads();
    }
  }
}

// per (b,h): att = softmax(logits rows) * (mask<0.1); store transposed, split bf16
__global__ __launch_bounds__(128)
void softmax_mask(const float* __restrict__ logits, const float* __restrict__ mask_u,
                  unsigned short* __restrict__ aTh, unsigned short* __restrict__ aTl)
{
  int z = blockIdx.x;
  int d = threadIdx.x;
  const float* row = logits + (size_t)z * 16384 + (size_t)d * 128;
  const float* mrow = mask_u + (size_t)z * 16384 + (size_t)d * 128;
  float mx = -3.4e38f;
  for (int e = 0; e < 128; ++e) mx = fmaxf(mx, row[e]);
  float s = 0.f;
  for (int e = 0; e < 128; ++e) s += __expf(row[e] - mx);
  float inv = 1.f / s;
  for (int e = 0; e < 128; ++e) {
    float a = __expf(row[e] - mx) * inv;
    a = (mrow[e] < SPARS) ? a : 0.f;
    unsigned short h = f2bf(a);
    aTh[(size_t)z * 16384 + (size_t)e * 128 + d] = h;
    aTl[(size_t)z * 16384 + (size_t)e * 128 + d] = f2bf(a - bf2f(h));
  }
}

// vb[b][c] = b_out[c] + sum_e Mh[b][c][e] * b_v[e]; one wave per (b,c)
__global__ __launch_bounds__(256)
void vbias_k(const unsigned short* __restrict__ Mh, const float* __restrict__ bv,
             const float* __restrict__ b_out, float* __restrict__ vb)
{
  int w = threadIdx.x >> 6, l = threadIdx.x & 63;
  int c = blockIdx.x * 4 + w;
  int b = blockIdx.y;
  const unsigned short* row = Mh + (size_t)b * 524288 + (size_t)c * 1024;
  float s = 0.f;
  for (int e = l; e < 1024; e += 64) s += bf2f(row[e]) * bv[e];
  for (int off = 32; off; off >>= 1) s += __shfl_down(s, off, 64);
  if (l == 0) vb[b * 512 + c] = b_out[c] + s;
}

extern "C" void kernel_launch(void* const* d_in, const int* in_sizes, int n_in,
                              void* d_out, int out_size, void* d_ws, size_t ws_size,
                              hipStream_t stream)
{
  const float* x      = (const float*)d_in[0];
  const float* w_qkv  = (const float*)d_in[1];
  const float* b_qkv  = (const float*)d_in[2];
  const float* w_out  = (const float*)d_in[3];
  const float* b_out  = (const float*)d_in[4];
  const float* mask_u = (const float*)d_in[5];
  float* out = (float*)d_out;
  (void)in_sizes; (void)n_in; (void)out_size; (void)ws_size;

  char* ws = (char*)d_ws;
  unsigned short* Xt   = (unsigned short*)ws;                    // 33,554,432
  unsigned short* Xhi  = (unsigned short*)(ws + 33554432);       // 33,554,432 (dead after G)
  unsigned short* Xlo  = (unsigned short*)(ws + 67108864);       // 33,554,432 (dead after G)
  unsigned short* Tph  = (unsigned short*)(ws + 33554432);       //  8,388,608 (overlay Xhi)
  unsigned short* Tpl  = (unsigned short*)(ws + 41943040);       //  8,388,608
  float*          Lg   = (float*)(ws + 50331648);                //  4,194,304
  unsigned short* aTh  = (unsigned short*)(ws + 54525952);       //  2,097,152
  unsigned short* aTl  = (unsigned short*)(ws + 56623104);       //  2,097,152
  unsigned short* Mh   = (unsigned short*)(ws + 67108864);       //  8,388,608 (overlay Xlo)
  unsigned short* P    = (unsigned short*)(ws + 75497472);       //  4,194,304
  float*          vb   = (float*)(ws + 79691776);                //     16,384
  float*          Gpart= (float*)(ws + 100663296);               // 33,554,432 (dead after reduce)
  unsigned short* Ghi  = (unsigned short*)(ws + 134217728);      //  4,194,304
  unsigned short* Glo  = (unsigned short*)(ws + 138412032);      //  4,194,304
  unsigned short* Whi  = (unsigned short*)(ws + 142606336);      //  3,145,728
  unsigned short* Wlo  = (unsigned short*)(ws + 145752064);      //  3,145,728
  unsigned short* Ohi  = (unsigned short*)(ws + 148897792);      //  1,048,576
  unsigned short* Olo  = (unsigned short*)(ws + 149946368);      //  1,048,576
  unsigned short* WvT  = Whi + 1048576;                          // reuse Whi's V rows

  const int BIG = 1 << 30;

  // 1. split+transpose x (vectorized)
  prep_x<<<dim3(32, 16, 8), 256, 0, stream>>>(x, Xhi, Xlo, Xt);
  // 2. split weights; WvT AFTER split_w (overwrites Whi's V rows)
  split_w<<<dim3(1536), 256, 0, stream>>>(w_qkv, Whi, Wlo, 393216);
  split_w<<<dim3(512), 256, 0, stream>>>(w_out, Ohi, Olo, 131072);
  transpose_wv<<<dim3(16, 32), dim3(32, 8), 0, stream>>>(w_qkv + 1048576, WvT);

  // 3. Gpart[chunk][b] = Xb Xb^T, K-split 4, UPPER-TRIANGLE tiles only (SYM)
  gemm_bt<128, 128, 3, 0, 1><<<dim3(10, 1, 32), 256, 0, stream>>>(
      Xhi, Xlo, Xhi, Xlo, Gpart, nullptr,
      1024, 4096, 4096, 512, 8, 8, 8,
      2097152LL, 1024LL, 2097152LL, 1024LL, 262144LL, 2097152LL, nullptr, 0LL, nullptr);

  // 4. reduce chunks + mirror lower triangle -> Ghi/Glo
  reduce_g_sym<<<dim3(10, 8), 256, 0, stream>>>(Gpart, Ghi, Glo);

  // 5. Tp_b = Wq * G_b (G symmetric -> NT), split out. 128x128 (r3-proven)
  gemm_bt<128, 128, 3, 2, 0><<<dim3(4, 8, 8), 256, 0, stream>>>(
      Whi, Wlo, Ghi, Glo, Tph, Tpl,
      512, 512, 512, 512, 1, 8, 8,
      0LL, 0LL, 262144LL, 0LL, 524288LL, 0LL, nullptr, 0LL, nullptr);

  // 6. L_{b,h} = Tp_{b,h} * Wk_h^T  (z=b*8+h)
  gemm_bt<64, 64, 3, 0, 0><<<dim3(2, 2, 64), 256, 0, stream>>>(
      Tph, Tpl, Whi + 524288, Wlo + 524288, Lg, nullptr,
      512, 512, 512, 128, BIG, 8, BIG,
      65536LL, 0LL, 65536LL, 0LL, 16384LL, 0LL, nullptr, 0LL, nullptr);

  // 7. softmax + mask -> attT hi/lo
  softmax_mask<<<dim3(64), 128, 0, stream>>>(Lg, mask_u, aTh, aTl);

  // 8. M_{b,h}[c,e'] = sum_d w_out[c,h*128+d] attT[e',d]  (z=b*8+h)
  gemm_bt<64, 64, 3, 1, 0><<<dim3(2, 8, 64), 256, 0, stream>>>(
      Ohi, Olo, aTh, aTl, Mh, nullptr,
      128, 1024, 128, 1024, 8, BIG, 8,
      128LL, 0LL, 16384LL, 0LL, 128LL, 524288LL, nullptr, 0LL, nullptr);

  // 9. vb[b][c] = b_out[c] + Mh_b[c,:] . b_v
  vbias_k<<<dim3(128, 8), 256, 0, stream>>>(Mh, b_qkv + 2048, b_out, vb);

  // 10. P_b[c,k] = sum_e Mh_b[c,e] WvT[k,e]  (plain bf16). 64x64 (r3-proven)
  gemm_bt<64, 64, 1, 1, 0><<<dim3(8, 8, 8), 256, 0, stream>>>(
      Mh, Mh, WvT, WvT, P, nullptr,
      1024, 1024, 1024, 512, BIG, 1, BIG,
      524288LL, 0LL, 0LL, 0LL, 262144LL, 0LL, nullptr, 0LL, nullptr);

  // 11. out_b[c,n] = sum_k P_b[c,k] Xt_b[n,k] + vb[b][c]. 128x128 (r3-proven)
  gemm_bt<128, 128, 1, 0, 0><<<dim3(32, 4, 8), 256, 0, stream>>>(
      P, P, Xt, Xt, out, nullptr,
      512, 512, 512, 4096, BIG, BIG, BIG,
      262144LL, 0LL, 2097152LL, 0LL, 2097152LL, 0LL, vb, 512LL, nullptr);
}